// Round 1
// baseline (37.509 us; speedup 1.0000x reference)
//
#include <hip/hip_runtime.h>
#include <math.h>

// Local banded attention: B=2, L=2048, H=8, E=D=64, window w=7 (band of 15).
// One 64-lane wave per (b,h,q); lane = channel index e.
// All loads/stores are 256B-coalesced per wave. Band loop is compile-time
// unrolled (template W) so the score array stays in registers.

constexpr int L_DIM = 2048;
constexpr int H_DIM = 8;
constexpr int E_DIM = 64;

template <int W>
__global__ __launch_bounds__(256) void local_attn_kernel(
    const float* __restrict__ q,
    const float* __restrict__ k,
    const float* __restrict__ v,
    float* __restrict__ out,
    int total_waves) {
  constexpr int NK = 2 * W + 1;
  const int wid = blockIdx.x * (blockDim.x >> 6) + (threadIdx.x >> 6);
  if (wid >= total_waves) return;
  const int lane = threadIdx.x & 63;

  // wid = (b*H + h)*L + l  -> consecutive waves share (b,h), walk l.
  const int l = wid % L_DIM;
  const int bh = wid / L_DIM;
  const int h = bh % H_DIM;
  const int b = bh / H_DIM;

  // element offset helper: idx(b, pos, h, lane) = ((b*L + pos)*H + h)*E + lane
  const size_t bhbase = ((size_t)b * L_DIM) * H_DIM + h;  // (b*L + 0)*H + h
  const float* qp = q + (bhbase + (size_t)l * H_DIM) * E_DIM + lane;

  const float scale = 0.125f;  // 1/sqrt(64)
  const float qe = (*qp) * scale;

  float sc[NK];
#pragma unroll
  for (int i = 0; i < NK; ++i) {
    const int kk = l - W + i;
    const bool valid = (kk >= 0) && (kk < L_DIM);
    const int kc = valid ? kk : (kk < 0 ? 0 : L_DIM - 1);
    const float ke = k[(bhbase + (size_t)kc * H_DIM) * E_DIM + lane];
    float s = qe * ke;
    // 64-lane butterfly reduction
    s += __shfl_xor(s, 32);
    s += __shfl_xor(s, 16);
    s += __shfl_xor(s, 8);
    s += __shfl_xor(s, 4);
    s += __shfl_xor(s, 2);
    s += __shfl_xor(s, 1);
    sc[i] = valid ? s : -INFINITY;
  }

  // softmax over the band (all lanes hold identical sc[])
  float m = sc[0];
#pragma unroll
  for (int i = 1; i < NK; ++i) m = fmaxf(m, sc[i]);
  float den = 0.0f;
#pragma unroll
  for (int i = 0; i < NK; ++i) {
    sc[i] = __expf(sc[i] - m);  // exp(-inf) = 0 for masked slots
    den += sc[i];
  }
  const float inv = 1.0f / den;

  float acc = 0.0f;
#pragma unroll
  for (int i = 0; i < NK; ++i) {
    const int kk = l - W + i;
    const int kc = (kk < 0) ? 0 : (kk >= L_DIM ? L_DIM - 1 : kk);
    const float ve = v[(bhbase + (size_t)kc * H_DIM) * E_DIM + lane];
    acc += sc[i] * ve;
  }

  out[(bhbase + (size_t)l * H_DIM) * E_DIM + lane] = acc * inv;
}

extern "C" void kernel_launch(void* const* d_in, const int* in_sizes, int n_in,
                              void* d_out, int out_size, void* d_ws, size_t ws_size,
                              hipStream_t stream) {
  const float* q = (const float*)d_in[0];
  const float* k = (const float*)d_in[1];
  const float* v = (const float*)d_in[2];
  float* out = (float*)d_out;

  const int B = in_sizes[0] / (L_DIM * H_DIM * E_DIM);  // = 2
  const int total_waves = B * H_DIM * L_DIM;            // 32768
  const int waves_per_block = 4;                        // 256 threads
  const int blocks = (total_waves + waves_per_block - 1) / waves_per_block;

  // w = ceil(1.2*log2(2048)/2) = 7 (compile-time)
  local_attn_kernel<7><<<blocks, 256, 0, stream>>>(q, k, v, out, total_waves);
}

// Round 2
// 21.604 us; speedup vs baseline: 1.7362x; 1.7362x over previous
//
#include <hip/hip_runtime.h>
#include <math.h>

// Local banded attention: B=2, L=2048, H=8, E=D=64, window w=7 (band of 15).
// 8 queries per wave (consecutive l), 8 lanes per query, 8 channels per lane
// (2x float4). Union band of 22 keys loaded once per wave, shared across the
// 8 query sub-groups via wave-broadcast addressing (address depends only on
// lane&7). Dot-product reduction = 3-step shfl_xor within 8-lane groups.

constexpr int L_DIM = 2048;
constexpr int H_DIM = 8;
constexpr int E_DIM = 64;
constexpr int W = 7;       // window: |i-j| <= 7 allowed
constexpr int QPW = 8;     // queries per wave
constexpr int NU = 2 * W + QPW;  // union band size = 22

__global__ __launch_bounds__(256) void local_attn_kernel(
    const float* __restrict__ q,
    const float* __restrict__ k,
    const float* __restrict__ v,
    float* __restrict__ out) {
  const int wid = blockIdx.x * 4 + (threadIdx.x >> 6);
  const int lane = threadIdx.x & 63;
  const int qsub = lane >> 3;   // which query in this wave [0,8)
  const int c = lane & 7;       // channel group [0,8): channels c*8..c*8+7

  // wid = ((b*H + h) * (L/8)) + lq
  const int lq = wid & (L_DIM / QPW - 1);
  const int bh = wid >> 8;  // L/QPW = 256
  const int h = bh & (H_DIM - 1);
  const int b = bh >> 3;
  const int l0 = lq * QPW;
  const int l = l0 + qsub;

  // element base: ((b*L + pos)*H + h)*64 + c*8
  const size_t bhb = (size_t)b * L_DIM * H_DIM + h;
  const float* qp = q + ((bhb + (size_t)l * H_DIM) << 6) + c * 8;

  const float scale = 0.125f;  // 1/sqrt(64)
  float4 q0 = *(const float4*)qp;
  float4 q1 = *(const float4*)(qp + 4);
  q0.x *= scale; q0.y *= scale; q0.z *= scale; q0.w *= scale;
  q1.x *= scale; q1.y *= scale; q1.z *= scale; q1.w *= scale;

  float sc[NU];
#pragma unroll
  for (int i = 0; i < NU; ++i) {
    const int kk = l0 - W + i;
    const int kc = (kk < 0) ? 0 : (kk >= L_DIM ? L_DIM - 1 : kk);
    const float* kp = k + ((bhb + (size_t)kc * H_DIM) << 6) + c * 8;
    const float4 k0 = *(const float4*)kp;
    const float4 k1 = *(const float4*)(kp + 4);
    float s = q0.x * k0.x + q0.y * k0.y + q0.z * k0.z + q0.w * k0.w +
              q1.x * k1.x + q1.y * k1.y + q1.z * k1.z + q1.w * k1.w;
    // reduce over the 8 lanes of this query sub-group
    s += __shfl_xor(s, 4);
    s += __shfl_xor(s, 2);
    s += __shfl_xor(s, 1);
    // key i valid for query qsub iff i in [qsub, qsub+2W], and kk in range
    const bool valid = (i >= qsub) && (i <= qsub + 2 * W) && (kk >= 0) && (kk < L_DIM);
    sc[i] = valid ? s : -INFINITY;
  }

  // softmax over the union band (invalid slots are -inf -> 0)
  float m = sc[0];
#pragma unroll
  for (int i = 1; i < NU; ++i) m = fmaxf(m, sc[i]);
  float den = 0.0f;
#pragma unroll
  for (int i = 0; i < NU; ++i) {
    sc[i] = __expf(sc[i] - m);
    den += sc[i];
  }
  const float inv = 1.0f / den;

  float4 a0 = {0.f, 0.f, 0.f, 0.f};
  float4 a1 = {0.f, 0.f, 0.f, 0.f};
#pragma unroll
  for (int i = 0; i < NU; ++i) {
    const int kk = l0 - W + i;
    const int kc = (kk < 0) ? 0 : (kk >= L_DIM ? L_DIM - 1 : kk);
    const float* vp = v + ((bhb + (size_t)kc * H_DIM) << 6) + c * 8;
    const float4 v0 = *(const float4*)vp;
    const float4 v1 = *(const float4*)(vp + 4);
    const float p = sc[i];
    a0.x += p * v0.x; a0.y += p * v0.y; a0.z += p * v0.z; a0.w += p * v0.w;
    a1.x += p * v1.x; a1.y += p * v1.y; a1.z += p * v1.z; a1.w += p * v1.w;
  }

  float* op = out + ((bhb + (size_t)l * H_DIM) << 6) + c * 8;
  a0.x *= inv; a0.y *= inv; a0.z *= inv; a0.w *= inv;
  a1.x *= inv; a1.y *= inv; a1.z *= inv; a1.w *= inv;
  *(float4*)op = a0;
  *(float4*)(op + 4) = a1;
}

extern "C" void kernel_launch(void* const* d_in, const int* in_sizes, int n_in,
                              void* d_out, int out_size, void* d_ws, size_t ws_size,
                              hipStream_t stream) {
  const float* q = (const float*)d_in[0];
  const float* k = (const float*)d_in[1];
  const float* v = (const float*)d_in[2];
  float* out = (float*)d_out;

  const int B = in_sizes[0] / (L_DIM * H_DIM * E_DIM);  // = 2
  const int total_waves = B * H_DIM * (L_DIM / QPW);    // 4096
  const int blocks = total_waves / 4;                   // 256-thread blocks

  local_attn_kernel<<<blocks, 256, 0, stream>>>(q, k, v, out);
}

// Round 3
// 14.516 us; speedup vs baseline: 2.5840x; 1.4883x over previous
//
#include <hip/hip_runtime.h>
#include <math.h>

// Local banded attention: B=2, L=2048, H=8, E=D=64, window w=7.
// Block = 512 threads (8 waves) handles 64 consecutive queries of one (b,h).
// K/V staged in LDS (80 rows = 64 + 2*8 halo, clamped) via async
// global_load_lds (16B, wave-uniform LDS base + lane*16 — linear layout).
// Wave handles 8 queries (8 lanes/query, 8 channels/lane, 2x float4).
// XCD swizzle: each XCD owns 2 full (b,h) slices -> K/V L2-resident.

constexpr int L_DIM = 2048;
constexpr int H_DIM = 8;
constexpr int E_DIM = 64;
constexpr int W = 7;             // |i-j| <= 7
constexpr int QPW = 8;           // queries per wave
constexpr int NU = 2 * W + QPW;  // union band per wave = 22
constexpr int TQ = 64;           // queries per block
constexpr int HALO = 8;
constexpr int ROWS = TQ + 2 * HALO;          // 80
constexpr int NCHUNK = ROWS * E_DIM * 4 / 1024;  // 20 x 1KB chunks per matrix

__global__ __launch_bounds__(512, 4) void local_attn_kernel(
    const float* __restrict__ q,
    const float* __restrict__ k,
    const float* __restrict__ v,
    float* __restrict__ out) {
  __shared__ float smem[2 * ROWS * E_DIM];  // 40 KB: K then V
  float* ks = smem;
  float* vs = smem + ROWS * E_DIM;

  // XCD-aware swizzle (gridDim.x = 512, divisible by 8):
  // xcd = blockIdx.x & 7 owns contiguous chunk of 64 logical blocks.
  const int cpx = gridDim.x >> 3;
  const int bid = (blockIdx.x & 7) * cpx + (blockIdx.x >> 3);

  const int tile = bid & (L_DIM / TQ - 1);  // 32 tiles
  const int bh = bid >> 5;
  const int h = bh & (H_DIM - 1);
  const int b = bh >> 3;
  const int l0 = tile * TQ;

  const int tid = threadIdx.x;
  const int wv = tid >> 6;      // wave id [0,8)
  const int lane = tid & 63;
  const int qsub = lane >> 3;   // query within wave [0,8)
  const int c = lane & 7;       // channel group [0,8)

  const size_t bhb = (size_t)b * L_DIM * H_DIM + h;

  const int l0w = l0 + wv * QPW;
  const int l = l0w + qsub;

  // Q -> registers (overlaps the async staging below)
  const float* qp = q + ((bhb + (size_t)l * H_DIM) << 6) + c * 8;
  float4 q0 = *(const float4*)qp;
  float4 q1 = *(const float4*)(qp + 4);

  // Async stage K (chunks 0..19) and V (chunks 20..39); wave wv takes ch%8==wv.
  // Chunk cc covers rows [cc*4, cc*4+4) of the 80-row tile; lane l supplies
  // row cc*4 + (l>>4), cols (l&15)*4 .. +3.  LDS dst is wave-uniform base;
  // HW adds lane*16.
  const int rsub = lane >> 4;
  const int col = (lane & 15) * 4;
  for (int ch = wv; ch < 2 * NCHUNK; ch += 8) {
    const int m = (ch >= NCHUNK) ? 1 : 0;
    const int cc = ch - m * NCHUNK;
    int rg = l0 - HALO + cc * 4 + rsub;
    rg = rg < 0 ? 0 : (rg > L_DIM - 1 ? L_DIM - 1 : rg);
    const float* src = (m ? v : k) + ((bhb + (size_t)rg * H_DIM) << 6) + col;
    float* dst = (m ? vs : ks) + cc * 256;  // 256 floats = 1 KB
    __builtin_amdgcn_global_load_lds(
        (const __attribute__((address_space(1))) void*)src,
        (__attribute__((address_space(3))) void*)dst, 16, 0, 0);
  }
  __syncthreads();

  const float scale = 0.125f;  // 1/sqrt(64)
  q0.x *= scale; q0.y *= scale; q0.z *= scale; q0.w *= scale;
  q1.x *= scale; q1.y *= scale; q1.z *= scale; q1.w *= scale;

  // Scores over the wave's union band: global row = l0w - 7 + i,
  // LDS row = wv*8 + 1 + i  (in [1,78]).
  float sc[NU];
#pragma unroll
  for (int i = 0; i < NU; ++i) {
    const int rl = wv * QPW + 1 + i;
    const float4 k0 = *(const float4*)&ks[rl * E_DIM + c * 8];
    const float4 k1 = *(const float4*)&ks[rl * E_DIM + c * 8 + 4];
    float s = q0.x * k0.x + q0.y * k0.y + q0.z * k0.z + q0.w * k0.w +
              q1.x * k1.x + q1.y * k1.y + q1.z * k1.z + q1.w * k1.w;
    s += __shfl_xor(s, 4);
    s += __shfl_xor(s, 2);
    s += __shfl_xor(s, 1);
    const int kk = l0w - W + i;
    const bool valid =
        (i >= qsub) && (i <= qsub + 2 * W) && (kk >= 0) && (kk < L_DIM);
    sc[i] = valid ? s : -INFINITY;
  }

  float mx = sc[0];
#pragma unroll
  for (int i = 1; i < NU; ++i) mx = fmaxf(mx, sc[i]);
  float den = 0.0f;
#pragma unroll
  for (int i = 0; i < NU; ++i) {
    sc[i] = __expf(sc[i] - mx);
    den += sc[i];
  }
  const float inv = 1.0f / den;

  float4 a0 = {0.f, 0.f, 0.f, 0.f};
  float4 a1 = {0.f, 0.f, 0.f, 0.f};
#pragma unroll
  for (int i = 0; i < NU; ++i) {
    const int rl = wv * QPW + 1 + i;
    const float4 v0 = *(const float4*)&vs[rl * E_DIM + c * 8];
    const float4 v1 = *(const float4*)&vs[rl * E_DIM + c * 8 + 4];
    const float p = sc[i];
    a0.x += p * v0.x; a0.y += p * v0.y; a0.z += p * v0.z; a0.w += p * v0.w;
    a1.x += p * v1.x; a1.y += p * v1.y; a1.z += p * v1.z; a1.w += p * v1.w;
  }

  float* op = out + ((bhb + (size_t)l * H_DIM) << 6) + c * 8;
  a0.x *= inv; a0.y *= inv; a0.z *= inv; a0.w *= inv;
  a1.x *= inv; a1.y *= inv; a1.z *= inv; a1.w *= inv;
  *(float4*)op = a0;
  *(float4*)(op + 4) = a1;
}

extern "C" void kernel_launch(void* const* d_in, const int* in_sizes, int n_in,
                              void* d_out, int out_size, void* d_ws, size_t ws_size,
                              hipStream_t stream) {
  const float* q = (const float*)d_in[0];
  const float* k = (const float*)d_in[1];
  const float* v = (const float*)d_in[2];
  float* out = (float*)d_out;

  const int B = in_sizes[0] / (L_DIM * H_DIM * E_DIM);  // = 2
  const int blocks = B * H_DIM * (L_DIM / TQ);          // 512

  local_attn_kernel<<<blocks, 512, 0, stream>>>(q, k, v, out);
}

// Round 4
// 12.269 us; speedup vs baseline: 3.0572x; 1.1831x over previous
//
#include <hip/hip_runtime.h>
#include <math.h>

// Local banded attention: B=2, L=2048, H=8, E=D=64, window w=7 (band=15).
// Block = 512 threads (8 waves) = 64 queries of one (b,h). K/V reg-staged
// into XOR-swizzled LDS (slot = rl*16 + (c4 ^ (rl&7))) so that per-query
// private band reads (8 distinct rows per wave) are bank-even.
// Wave: 8 queries x 8 lanes x 8 channels. Dot reduction = 3 DPP adds
// (quad_perm xor1, quad_perm xor2, row_half_mirror) - VALU pipe, not DS.

constexpr int L_DIM = 2048;
constexpr int H_DIM = 8;
constexpr int E_DIM = 64;
constexpr int W = 7;
constexpr int NK = 2 * W + 1;        // 15 band positions per query
constexpr int TQ = 64;               // queries per block
constexpr int HALO = 8;
constexpr int ROWS = TQ + 2 * HALO;  // 80 staged rows

template <int CTRL>
__device__ __forceinline__ float dpp_add(float s) {
  int t = __builtin_amdgcn_mov_dpp(__builtin_bit_cast(int, s), CTRL, 0xF, 0xF, true);
  return s + __builtin_bit_cast(float, t);
}

__global__ __launch_bounds__(512, 4) void local_attn_kernel(
    const float* __restrict__ q,
    const float* __restrict__ k,
    const float* __restrict__ v,
    float* __restrict__ out) {
  __shared__ float ks[ROWS * E_DIM];
  __shared__ float vs[ROWS * E_DIM];

  // XCD-aware swizzle (grid = 512, divisible by 8)
  const int cpx = gridDim.x >> 3;
  const int bid = (blockIdx.x & 7) * cpx + (blockIdx.x >> 3);

  const int tile = bid & (L_DIM / TQ - 1);  // 32 tiles
  const int bh = bid >> 5;
  const int h = bh & (H_DIM - 1);
  const int b = bh >> 3;
  const int l0 = tile * TQ;

  const int tid = threadIdx.x;
  const int wv = tid >> 6;     // wave [0,8)
  const int lane = tid & 63;
  const int qsub = lane >> 3;  // query within wave [0,8)
  const int c = lane & 7;      // channel group [0,8) -> channels c*8..c*8+7

  const size_t bhb = (size_t)b * L_DIM * H_DIM + h;

  // ---- staging: global -> regs (issued early, fire-and-forget) ----
  // 40 chunks of 4 rows x 64 floats (K: 0..19, V: 20..39); wave takes 5.
  const int rsub = lane >> 4;  // row within chunk
  const int c4 = lane & 15;    // 16B column group
  float4 stg[5];
  int stg_slot[5];
#pragma unroll
  for (int t = 0; t < 5; ++t) {
    const int ch = wv + t * 8;
    const int m = (ch >= 20) ? 1 : 0;
    const int cc = ch - m * 20;
    const int rl = cc * 4 + rsub;  // LDS row 0..79
    int rg = l0 - HALO + rl;
    rg = rg < 0 ? 0 : (rg > L_DIM - 1 ? L_DIM - 1 : rg);
    const float* src =
        (m ? v : k) + ((bhb + (size_t)rg * H_DIM) << 6) + c4 * 4;
    stg[t] = *(const float4*)src;
    stg_slot[t] = rl * 16 + (c4 ^ (rl & 7));
  }

  // ---- Q -> regs (overlaps staging latency) ----
  const int l0w = l0 + wv * 8;
  const int l = l0w + qsub;
  const float* qp = q + ((bhb + (size_t)l * H_DIM) << 6) + c * 8;
  float4 q0 = *(const float4*)qp;
  float4 q1 = *(const float4*)(qp + 4);
  const float scale = 0.125f;  // 1/sqrt(64)
  q0.x *= scale; q0.y *= scale; q0.z *= scale; q0.w *= scale;
  q1.x *= scale; q1.y *= scale; q1.z *= scale; q1.w *= scale;

  // ---- swizzled LDS writes ----
#pragma unroll
  for (int t = 0; t < 5; ++t) {
    const int ch = wv + t * 8;
    float* dst = ((ch >= 20) ? vs : ks) + stg_slot[t] * 4;
    *(float4*)dst = stg[t];
  }
  __syncthreads();

  // ---- scores: each query group walks its own 15-key band ----
  // LDS row for band pos j: rl = wv*8 + 1 + qsub + j  (in [1,78])
  const int base_rl = wv * 8 + 1 + qsub;
  float sc[NK];
#pragma unroll
  for (int j = 0; j < NK; ++j) {
    const int rl = base_rl + j;
    const int s8 = rl & 7;
    const float4 k0 = *(const float4*)&ks[(rl * 16 + ((2 * c) ^ s8)) * 4];
    const float4 k1 = *(const float4*)&ks[(rl * 16 + ((2 * c + 1) ^ s8)) * 4];
    float s = q0.x * k0.x + q0.y * k0.y + q0.z * k0.z + q0.w * k0.w +
              q1.x * k1.x + q1.y * k1.y + q1.z * k1.z + q1.w * k1.w;
    s = dpp_add<0xB1>(s);   // xor 1 (quad_perm [1,0,3,2])
    s = dpp_add<0x4E>(s);   // xor 2 (quad_perm [2,3,0,1])
    s = dpp_add<0x141>(s);  // 8-lane half-row mirror
    const int kk = l0w + qsub - W + j;
    sc[j] = ((unsigned)kk < (unsigned)L_DIM) ? s : -INFINITY;
  }

  // ---- softmax over 15 band scores (identical in all 8 lanes of group) ----
  float mx = sc[0];
#pragma unroll
  for (int j = 1; j < NK; ++j) mx = fmaxf(mx, sc[j]);
  float den = 0.0f;
#pragma unroll
  for (int j = 0; j < NK; ++j) {
    sc[j] = __expf(sc[j] - mx);
    den += sc[j];
  }
  const float inv = __builtin_amdgcn_rcpf(den);

  // ---- PV: same private-row walk over V ----
  float4 a0 = {0.f, 0.f, 0.f, 0.f};
  float4 a1 = {0.f, 0.f, 0.f, 0.f};
#pragma unroll
  for (int j = 0; j < NK; ++j) {
    const int rl = base_rl + j;
    const int s8 = rl & 7;
    const float4 v0 = *(const float4*)&vs[(rl * 16 + ((2 * c) ^ s8)) * 4];
    const float4 v1 = *(const float4*)&vs[(rl * 16 + ((2 * c + 1) ^ s8)) * 4];
    const float p = sc[j];
    a0.x += p * v0.x; a0.y += p * v0.y; a0.z += p * v0.z; a0.w += p * v0.w;
    a1.x += p * v1.x; a1.y += p * v1.y; a1.z += p * v1.z; a1.w += p * v1.w;
  }

  float* op = out + ((bhb + (size_t)l * H_DIM) << 6) + c * 8;
  a0.x *= inv; a0.y *= inv; a0.z *= inv; a0.w *= inv;
  a1.x *= inv; a1.y *= inv; a1.z *= inv; a1.w *= inv;
  *(float4*)op = a0;
  *(float4*)(op + 4) = a1;
}

extern "C" void kernel_launch(void* const* d_in, const int* in_sizes, int n_in,
                              void* d_out, int out_size, void* d_ws, size_t ws_size,
                              hipStream_t stream) {
  const float* q = (const float*)d_in[0];
  const float* k = (const float*)d_in[1];
  const float* v = (const float*)d_in[2];
  float* out = (float*)d_out;

  const int B = in_sizes[0] / (L_DIM * H_DIM * E_DIM);  // = 2
  const int blocks = B * H_DIM * (L_DIM / TQ);          // 512

  local_attn_kernel<<<blocks, 512, 0, stream>>>(q, k, v, out);
}